// Round 13
// baseline (110.188 us; speedup 1.0000x reference)
//
#include <hip/hip_runtime.h>
#include <hip/hip_bf16.h>

// GaussSpatialConv: out[i,:] = softmax_j(-||x_i-y_j||^2 * 50) @ y_fea
// B=1, N=M=12288, D=16, fp32.
//
// R13: trans-pipe elimination. kacc's time fits a SUM-of-pipes model
// (VALU 5.8 + trans 15.4 + LDS 11.5 + MFMA 2.4 us/CU ~= measured 38 us):
// in-order waves at 3/SIMD can't overlap the ds_read->fma->exp2->cvt->mfma
// chain. Replace v_exp_f32 with exp-free 2^g = ldexp(poly3(f), rndne(g)):
// ~5 full-rate VALU insts/value (poly packed), rel err <= 0.03% << bf16 ulp.
// Rest = R9 measured-best: CH=16, LDS-staged Y SoA, analytic shift (no kmax),
// v_cvt_pk_bf16_f32 pack, fb prefetch, plain partial stores, 3 nodes.
// Harness 0xAA ws-fill (~43-47 us, 268 MB) is fixed overhead.

#define NROWS 12288
#define MCOLS 12288
#define DFEA  16
#define CC 72.13475204444817f   // 50 * log2(e)
#define SHIFT 112.0f

typedef __attribute__((ext_vector_type(8))) short bf16x8;
typedef __attribute__((ext_vector_type(4))) float f32x4;
typedef __attribute__((ext_vector_type(2))) float f32x2;

__device__ __forceinline__ f32x2 sp2(float v) { return (f32x2){v, v}; }
__device__ __forceinline__ f32x2 fma2(f32x2 a, f32x2 b, f32x2 c) {
    return __builtin_elementwise_fma(a, b, c);
}

// exp-free 2^g: n=rndne(g), f=g-n in [-0.5,0.5], deg-3 poly, ldexp.
// max rel err ~2.5e-4 (<< bf16 0.4% ulp). Full-rate VALU only, no trans pipe.
#define EC1 0.69314718f
#define EC2 0.24022651f
#define EC3 0.05550411f
__device__ __forceinline__ f32x2 exp2_poly2(f32x2 g) {
    float n0 = __builtin_roundevenf(g.x);
    float n1 = __builtin_roundevenf(g.y);
    f32x2 f = g - (f32x2){n0, n1};                       // v_pk_add (sub)
    f32x2 p = fma2(f, fma2(f, fma2(f, sp2(EC3), sp2(EC2)), sp2(EC1)), sp2(1.0f));
    f32x2 w;
    w.x = __builtin_amdgcn_ldexpf(p.x, (int)n0);
    w.y = __builtin_amdgcn_ldexpf(p.y, (int)n1);
    return w;
}

// pack bf16(a) | bf16(b)<<16
#if __has_builtin(__builtin_amdgcn_cvt_pk_bf16_f32)
typedef __attribute__((ext_vector_type(2))) __bf16 bf16x2_t;
__device__ __forceinline__ unsigned pk_bf16(float a, float b) {
    bf16x2_t v = __builtin_amdgcn_cvt_pk_bf16_f32(a, b);
    return __builtin_bit_cast(unsigned, v);        // 1 inst: v_cvt_pk_bf16_f32
}
#else
__device__ __forceinline__ unsigned pk_bf16(float a, float b) {
    unsigned ua = __float_as_uint(a) + 0x8000u;
    unsigned ub = __float_as_uint(b) + 0x8000u;
    return __builtin_amdgcn_perm(ub, ua, 0x07060302);  // 3 inst fallback
}
#endif

// ---------------------------------------------------------------- kprep ----
// 96 blocks: feaB b-frag repack, coalesced via LDS (128 js per block).
// feaB layout: [384 k-tiles][64 lanes] uint4 (8 bf16 per lane).
__global__ __launch_bounds__(256) void kprep_kernel(const float* __restrict__ fea,
                                                    uint4* __restrict__ feaB) {
    __shared__ float fs[128 * DFEA];   // 8 KB
    int b = blockIdx.x, t = threadIdx.x;
    int j0 = b * 128;
    const float4* src = (const float4*)(fea + (size_t)j0 * DFEA);
    float4* dst = (float4*)fs;
    dst[t] = src[t];
    dst[t + 256] = src[t + 256];
    __syncthreads();
    int tile = t >> 6, lane = t & 63;
    int jb = tile * 32 + ((lane >> 4) << 3);
    int col = lane & 15;
    float v[8];
    #pragma unroll
    for (int jj = 0; jj < 8; ++jj) v[jj] = fs[(jb + jj) * DFEA + col];
    uint4 o;
    o.x = pk_bf16(v[0], v[1]); o.y = pk_bf16(v[2], v[3]);
    o.z = pk_bf16(v[4], v[5]); o.w = pk_bf16(v[6], v[7]);
    feaB[b * 256 + t] = o;
}

// ---------------------------------------------------------------- kacc ----
// 48*CH blocks x 256 threads: rb = b/CH (48 row-blocks of 256 rows),
// jc = b%CH (JPB js = JPB/32 k-tiles). LDS-staged Y SoA; fb prefetched.
// Plain partial stores; no atomics, no fences. Poly exp (no trans pipe).
template <int CH>
__global__ __launch_bounds__(256, 3) void kacc_kernel(const float* __restrict__ x,
                                                      const float* __restrict__ y,
                                                      const uint4* __restrict__ feaB,
                                                      float* __restrict__ spart,
                                                      float* __restrict__ apart) {
    constexpr int JPB = MCOLS / CH;
    constexpr int KT  = JPB / 32;
    __shared__ float Ys0[JPB], Ys1[JPB], Ys2[JPB], Ysw[JPB];
    int t  = threadIdx.x;
    int rb = blockIdx.x / CH;
    int jc = blockIdx.x % CH;
    int j0 = jc * JPB;

    for (int i = t; i < JPB; i += 256) {
        float a = y[3 * (j0 + i) + 0];
        float c = y[3 * (j0 + i) + 1];
        float d = y[3 * (j0 + i) + 2];
        Ys0[i] = 2.0f * CC * a; Ys1[i] = 2.0f * CC * c; Ys2[i] = 2.0f * CC * d;
        Ysw[i] = -CC * (a * a + c * c + d * d);
    }
    __syncthreads();

    int wv   = t >> 6;
    int lane = t & 63;
    int grp  = lane >> 4;
    int m    = lane & 15;
    int rowbase = rb * 256 + wv * 64;

    float X0[4], X1[4], X2[4], Gm[4];
    #pragma unroll
    for (int r = 0; r < 4; ++r) {
        int row = rowbase + r * 16 + m;
        X0[r] = x[3 * row + 0]; X1[r] = x[3 * row + 1]; X2[r] = x[3 * row + 2];
        // analytic shift: arg = SHIFT - CC*d2 <= SHIFT (112); softmax shift-inv
        Gm[r] = CC * (X0[r] * X0[r] + X1[r] * X1[r] + X2[r] * X2[r]) - SHIFT;
    }

    const uint4* fb = feaB + (size_t)jc * (JPB * 2) + lane;   // + kt*64 per tile

    const bf16x8 ones = (bf16x8){(short)0x3F80, (short)0x3F80, (short)0x3F80, (short)0x3F80,
                                 (short)0x3F80, (short)0x3F80, (short)0x3F80, (short)0x3F80};
    f32x4 acc[4], accs[4];
    #pragma unroll
    for (int r = 0; r < 4; ++r) {
        acc[r]  = (f32x4){0.f, 0.f, 0.f, 0.f};
        accs[r] = (f32x4){0.f, 0.f, 0.f, 0.f};
    }

    uint4 bnext = fb[0];
    #pragma unroll 2
    for (int kt = 0; kt < KT; ++kt) {
        bf16x8 bfrag = __builtin_bit_cast(bf16x8, bnext);
        if (kt + 1 < KT) bnext = fb[(kt + 1) * 64];   // prefetch next tile

        int jb = kt * 32 + grp * 8;   // this lane's 8 k-positions
        f32x4 A0 = *(const f32x4*)&Ys0[jb], B0 = *(const f32x4*)&Ys0[jb + 4];
        f32x4 A1 = *(const f32x4*)&Ys1[jb], B1 = *(const f32x4*)&Ys1[jb + 4];
        f32x4 A2 = *(const f32x4*)&Ys2[jb], B2 = *(const f32x4*)&Ys2[jb + 4];
        f32x4 Aw = *(const f32x4*)&Ysw[jb], Bw = *(const f32x4*)&Ysw[jb + 4];

        #pragma unroll
        for (int r = 0; r < 4; ++r) {
            f32x2 x0 = sp2(X0[r]), x1 = sp2(X1[r]), x2 = sp2(X2[r]);
            f32x2 gm = sp2(Gm[r]);
            f32x2 g0 = fma2(x0, A0.xy, fma2(x1, A1.xy, fma2(x2, A2.xy, Aw.xy))) - gm;
            f32x2 g1 = fma2(x0, A0.zw, fma2(x1, A1.zw, fma2(x2, A2.zw, Aw.zw))) - gm;
            f32x2 g2 = fma2(x0, B0.xy, fma2(x1, B1.xy, fma2(x2, B2.xy, Bw.xy))) - gm;
            f32x2 g3 = fma2(x0, B0.zw, fma2(x1, B1.zw, fma2(x2, B2.zw, Bw.zw))) - gm;
            f32x2 w0 = exp2_poly2(g0);
            f32x2 w1 = exp2_poly2(g1);
            f32x2 w2 = exp2_poly2(g2);
            f32x2 w3 = exp2_poly2(g3);
            union { unsigned u[4]; bf16x8 v; } af;
            af.u[0] = pk_bf16(w0.x, w0.y);
            af.u[1] = pk_bf16(w1.x, w1.y);
            af.u[2] = pk_bf16(w2.x, w2.y);
            af.u[3] = pk_bf16(w3.x, w3.y);
            acc[r]  = __builtin_amdgcn_mfma_f32_16x16x32_bf16(af.v, bfrag, acc[r], 0, 0, 0);
            accs[r] = __builtin_amdgcn_mfma_f32_16x16x32_bf16(af.v, ones,  accs[r], 0, 0, 0);
        }
    }

    // plain-store partial epilogue. C/D layout: lane (grp,m) holds D[grp*4+reg][m].
    float* ap = apart + (size_t)jc * (NROWS * DFEA);
    #pragma unroll
    for (int r = 0; r < 4; ++r) {
        #pragma unroll
        for (int reg = 0; reg < 4; ++reg) {
            int orow = rowbase + r * 16 + grp * 4 + reg;
            ap[(size_t)orow * DFEA + m] = acc[r][reg];
        }
        if (m == 0) {
            #pragma unroll
            for (int reg = 0; reg < 4; ++reg)
                spart[jc * NROWS + rowbase + r * 16 + grp * 4 + reg] = accs[r][reg];
        }
    }
}

// ---------------------------------------------------------------- kdiv ----
template <int CH>
__global__ __launch_bounds__(256) void kdiv_kernel(const float* __restrict__ spart,
                                                   const float* __restrict__ apart,
                                                   float* __restrict__ out) {
    int tid = blockIdx.x * 256 + threadIdx.x;   // 196608 threads
    int row = tid >> 4;
    float s = 0.0f;
    #pragma unroll
    for (int c = 0; c < CH; ++c) s += spart[c * NROWS + row];
    float o = 0.0f;
    #pragma unroll
    for (int c = 0; c < CH; ++c) o += apart[(size_t)c * (NROWS * DFEA) + tid];
    out[tid] = o / s;
}

// -------------------------------------------------------------- launch ----
// ws (floats): spart CH*N | feaB 98304 (2N uint4) | apart CH*N*16  (~14 MB)
extern "C" void kernel_launch(void* const* d_in, const int* in_sizes, int n_in,
                              void* d_out, int out_size, void* d_ws, size_t ws_size,
                              hipStream_t stream) {
    const float* x   = (const float*)d_in[0];   // [N,3]
    const float* y   = (const float*)d_in[1];   // [M,3]
    const float* fea = (const float*)d_in[2];   // [M,16]
    float* out = (float*)d_out;                 // [N,16]

    constexpr int CH = 16;
    float* wsf   = (float*)d_ws;
    float* spart = wsf;                          // CH*N
    uint4* feaB  = (uint4*)(spart + CH * NROWS); // 2N uint4 = 98304 f32
    float* apart = (float*)feaB + 98304;         // CH*N*16

    kprep_kernel<<<dim3(96), 256, 0, stream>>>(fea, feaB);
    kacc_kernel<CH><<<dim3(48 * CH), 256, 0, stream>>>(x, y, feaB, spart, apart);
    kdiv_kernel<CH><<<dim3(768), 256, 0, stream>>>(spart, apart, out);
}

// Round 14
// 96.023 us; speedup vs baseline: 1.1475x; 1.1475x over previous
//
#include <hip/hip_runtime.h>
#include <hip/hip_bf16.h>

// GaussSpatialConv: out[i,:] = softmax_j(-||x_i-y_j||^2 * 50) @ y_fea
// B=1, N=M=12288, D=16, fp32.
//
// R14: verbatim revert to R9 -- the measured-best configuration (95.9 us).
// R10 (CH=32), R11 (unroll/prefetch/HW-pack), R12 (VGPR cap), R13 (poly exp)
// all measured equal-or-worse; every structural lever has been A/B'd:
//   win:  MFMA restructure (R3), atomic/fence-free partials (R7),
//         analytic shift / kmax elimination (R9)
//   lose: L2-direct Y (R8), agent fence (R6), poly exp (R13)
//   neutral: occupancy, ILP/VGPR, packs, prefetch (R10-R12)
// Floor accounting: ~44 us harness 0xAA ws-fill (268 MB, fixed) +
// ~38 us kacc (latency-bound at 3 waves/SIMD) + ~13 us kprep/kdiv/gaps.

#define NROWS 12288
#define MCOLS 12288
#define DFEA  16
#define CC 72.13475204444817f   // 50 * log2(e)
#define SHIFT 112.0f

typedef __attribute__((ext_vector_type(8))) short bf16x8;
typedef __attribute__((ext_vector_type(4))) float f32x4;
typedef __attribute__((ext_vector_type(2))) float f32x2;

#if __has_builtin(__builtin_amdgcn_exp2f)
#define EXP2(x) __builtin_amdgcn_exp2f(x)
#else
#define EXP2(x) exp2f(x)
#endif

__device__ __forceinline__ f32x2 sp2(float v) { return (f32x2){v, v}; }
__device__ __forceinline__ f32x2 fma2(f32x2 a, f32x2 b, f32x2 c) {
    return __builtin_elementwise_fma(a, b, c);
}

// pack bf16(a) | bf16(b)<<16, round-half-up: 2 v_add_u32 + 1 v_perm_b32
__device__ __forceinline__ unsigned pk_bf16(float a, float b) {
    unsigned ua = __float_as_uint(a) + 0x8000u;
    unsigned ub = __float_as_uint(b) + 0x8000u;
    return __builtin_amdgcn_perm(ub, ua, 0x07060302);  // [hi16(ub):hi16(ua)]
}

// ---------------------------------------------------------------- kprep ----
// 96 blocks: feaB b-frag repack, coalesced via LDS (128 js per block).
// feaB layout: [384 k-tiles][64 lanes] uint4 (8 bf16 per lane).
__global__ __launch_bounds__(256) void kprep_kernel(const float* __restrict__ fea,
                                                    uint4* __restrict__ feaB) {
    __shared__ float fs[128 * DFEA];   // 8 KB
    int b = blockIdx.x, t = threadIdx.x;
    int j0 = b * 128;
    const float4* src = (const float4*)(fea + (size_t)j0 * DFEA);
    float4* dst = (float4*)fs;
    dst[t] = src[t];
    dst[t + 256] = src[t + 256];
    __syncthreads();
    int tile = t >> 6, lane = t & 63;
    int jb = tile * 32 + ((lane >> 4) << 3);
    int col = lane & 15;
    float v[8];
    #pragma unroll
    for (int jj = 0; jj < 8; ++jj) v[jj] = fs[(jb + jj) * DFEA + col];
    uint4 o;
    o.x = pk_bf16(v[0], v[1]); o.y = pk_bf16(v[2], v[3]);
    o.z = pk_bf16(v[4], v[5]); o.w = pk_bf16(v[6], v[7]);
    feaB[b * 256 + t] = o;
}

// ---------------------------------------------------------------- kacc ----
// 48*CH blocks x 256 threads: rb = b/CH (48 row-blocks of 256 rows),
// jc = b%CH (JPB js = JPB/32 k-tiles). LDS-staged Y SoA (R7 core).
// Plain partial stores; no atomics, no fences.
template <int CH>
__global__ __launch_bounds__(256, 4) void kacc_kernel(const float* __restrict__ x,
                                                      const float* __restrict__ y,
                                                      const uint4* __restrict__ feaB,
                                                      float* __restrict__ spart,
                                                      float* __restrict__ apart) {
    constexpr int JPB = MCOLS / CH;
    constexpr int KT  = JPB / 32;
    __shared__ float Ys0[JPB], Ys1[JPB], Ys2[JPB], Ysw[JPB];
    int t  = threadIdx.x;
    int rb = blockIdx.x / CH;
    int jc = blockIdx.x % CH;
    int j0 = jc * JPB;

    for (int i = t; i < JPB; i += 256) {
        float a = y[3 * (j0 + i) + 0];
        float c = y[3 * (j0 + i) + 1];
        float d = y[3 * (j0 + i) + 2];
        Ys0[i] = 2.0f * CC * a; Ys1[i] = 2.0f * CC * c; Ys2[i] = 2.0f * CC * d;
        Ysw[i] = -CC * (a * a + c * c + d * d);
    }
    __syncthreads();

    int wv   = t >> 6;
    int lane = t & 63;
    int grp  = lane >> 4;
    int m    = lane & 15;
    int rowbase = rb * 256 + wv * 64;

    float X0[4], X1[4], X2[4], Gm[4];
    #pragma unroll
    for (int r = 0; r < 4; ++r) {
        int row = rowbase + r * 16 + m;
        X0[r] = x[3 * row + 0]; X1[r] = x[3 * row + 1]; X2[r] = x[3 * row + 2];
        // analytic shift: arg = SHIFT - CC*d2 <= SHIFT (112); softmax shift-inv
        Gm[r] = CC * (X0[r] * X0[r] + X1[r] * X1[r] + X2[r] * X2[r]) - SHIFT;
    }

    const uint4* fb = feaB + (size_t)jc * (JPB * 2) + lane;   // + kt*64 per tile

    const bf16x8 ones = (bf16x8){(short)0x3F80, (short)0x3F80, (short)0x3F80, (short)0x3F80,
                                 (short)0x3F80, (short)0x3F80, (short)0x3F80, (short)0x3F80};
    f32x4 acc[4], accs[4];
    #pragma unroll
    for (int r = 0; r < 4; ++r) {
        acc[r]  = (f32x4){0.f, 0.f, 0.f, 0.f};
        accs[r] = (f32x4){0.f, 0.f, 0.f, 0.f};
    }

    for (int kt = 0; kt < KT; ++kt) {
        int jb = kt * 32 + grp * 8;   // this lane's 8 k-positions
        f32x4 A0 = *(const f32x4*)&Ys0[jb], B0 = *(const f32x4*)&Ys0[jb + 4];
        f32x4 A1 = *(const f32x4*)&Ys1[jb], B1 = *(const f32x4*)&Ys1[jb + 4];
        f32x4 A2 = *(const f32x4*)&Ys2[jb], B2 = *(const f32x4*)&Ys2[jb + 4];
        f32x4 Aw = *(const f32x4*)&Ysw[jb], Bw = *(const f32x4*)&Ysw[jb + 4];
        bf16x8 bfrag = __builtin_bit_cast(bf16x8, fb[kt * 64]);

        #pragma unroll
        for (int r = 0; r < 4; ++r) {
            f32x2 x0 = sp2(X0[r]), x1 = sp2(X1[r]), x2 = sp2(X2[r]);
            f32x2 gm = sp2(Gm[r]);
            f32x2 g0 = fma2(x0, A0.xy, fma2(x1, A1.xy, fma2(x2, A2.xy, Aw.xy))) - gm;
            f32x2 g1 = fma2(x0, A0.zw, fma2(x1, A1.zw, fma2(x2, A2.zw, Aw.zw))) - gm;
            f32x2 g2 = fma2(x0, B0.xy, fma2(x1, B1.xy, fma2(x2, B2.xy, Bw.xy))) - gm;
            f32x2 g3 = fma2(x0, B0.zw, fma2(x1, B1.zw, fma2(x2, B2.zw, Bw.zw))) - gm;
            union { unsigned u[4]; bf16x8 v; } af;
            af.u[0] = pk_bf16(EXP2(g0.x), EXP2(g0.y));
            af.u[1] = pk_bf16(EXP2(g1.x), EXP2(g1.y));
            af.u[2] = pk_bf16(EXP2(g2.x), EXP2(g2.y));
            af.u[3] = pk_bf16(EXP2(g3.x), EXP2(g3.y));
            acc[r]  = __builtin_amdgcn_mfma_f32_16x16x32_bf16(af.v, bfrag, acc[r], 0, 0, 0);
            accs[r] = __builtin_amdgcn_mfma_f32_16x16x32_bf16(af.v, ones,  accs[r], 0, 0, 0);
        }
    }

    // plain-store partial epilogue. C/D layout: lane (grp,m) holds D[grp*4+reg][m].
    float* ap = apart + (size_t)jc * (NROWS * DFEA);
    #pragma unroll
    for (int r = 0; r < 4; ++r) {
        #pragma unroll
        for (int reg = 0; reg < 4; ++reg) {
            int orow = rowbase + r * 16 + grp * 4 + reg;
            ap[(size_t)orow * DFEA + m] = acc[r][reg];
        }
        if (m == 0) {
            #pragma unroll
            for (int reg = 0; reg < 4; ++reg)
                spart[jc * NROWS + rowbase + r * 16 + grp * 4 + reg] = accs[r][reg];
        }
    }
}

// ---------------------------------------------------------------- kdiv ----
template <int CH>
__global__ __launch_bounds__(256) void kdiv_kernel(const float* __restrict__ spart,
                                                   const float* __restrict__ apart,
                                                   float* __restrict__ out) {
    int tid = blockIdx.x * 256 + threadIdx.x;   // 196608 threads
    int row = tid >> 4;
    float s = 0.0f;
    #pragma unroll
    for (int c = 0; c < CH; ++c) s += spart[c * NROWS + row];
    float o = 0.0f;
    #pragma unroll
    for (int c = 0; c < CH; ++c) o += apart[(size_t)c * (NROWS * DFEA) + tid];
    out[tid] = o / s;
}

// -------------------------------------------------------------- launch ----
// ws (floats): spart CH*N | feaB 98304 (2N uint4) | apart CH*N*16  (~14 MB)
extern "C" void kernel_launch(void* const* d_in, const int* in_sizes, int n_in,
                              void* d_out, int out_size, void* d_ws, size_t ws_size,
                              hipStream_t stream) {
    const float* x   = (const float*)d_in[0];   // [N,3]
    const float* y   = (const float*)d_in[1];   // [M,3]
    const float* fea = (const float*)d_in[2];   // [M,16]
    float* out = (float*)d_out;                 // [N,16]

    constexpr int CH = 16;
    float* wsf   = (float*)d_ws;
    float* spart = wsf;                          // CH*N
    uint4* feaB  = (uint4*)(spart + CH * NROWS); // 2N uint4 = 98304 f32
    float* apart = (float*)feaB + 98304;         // CH*N*16

    kprep_kernel<<<dim3(96), 256, 0, stream>>>(fea, feaB);
    kacc_kernel<CH><<<dim3(48 * CH), 256, 0, stream>>>(x, y, feaB, spart, apart);
    kdiv_kernel<CH><<<dim3(768), 256, 0, stream>>>(spart, apart, out);
}